// Round 6
// baseline (766.493 us; speedup 1.0000x reference)
//
#include <hip/hip_runtime.h>

#define NN 262144   // nodes
#define NE 1048576  // edges
#define NG 8192     // graphs
#define FD 64       // feature dim
#define AD 8        // adduct dim
#define DN 512      // dense dim

__device__ __forceinline__ int lowerBound(const int* __restrict__ a, int n, int v) {
  int lo = 0, hi = n;
  while (lo < hi) { int mid = (lo + hi) >> 1; if (a[mid] < v) lo = mid + 1; else hi = mid; }
  return lo;
}

// ---------------- CSR build ----------------
__global__ void k_count(const int* __restrict__ dst, int* __restrict__ counts) {
  int e = blockIdx.x * 256 + threadIdx.x;
  if (e < NE) atomicAdd(&counts[dst[e]], 1);
}

__global__ void k_scan1(const int* __restrict__ counts, int* __restrict__ rp,
                        int* __restrict__ bsum) {
  __shared__ int s[256];
  int tid = threadIdx.x;
  int i = blockIdx.x * 256 + tid;
  int orig = counts[i];
  s[tid] = orig;
  __syncthreads();
  for (int off = 1; off < 256; off <<= 1) {
    int v = (tid >= off) ? s[tid - off] : 0;
    __syncthreads();
    s[tid] += v;
    __syncthreads();
  }
  rp[i] = s[tid] - orig;  // block-local exclusive scan
  if (tid == 255) bsum[blockIdx.x] = s[tid];
}

__global__ void k_scan2(int* __restrict__ bsum) {
  __shared__ int s[1024];
  int tid = threadIdx.x;
  int orig = bsum[tid];
  s[tid] = orig;
  __syncthreads();
  for (int off = 1; off < 1024; off <<= 1) {
    int v = (tid >= off) ? s[tid - off] : 0;
    __syncthreads();
    s[tid] += v;
    __syncthreads();
  }
  bsum[tid] = s[tid] - orig;  // exclusive
}

__global__ void k_scan3(const int* __restrict__ counts, int* __restrict__ rp,
                        const int* __restrict__ bsum, int* __restrict__ cursor,
                        float* __restrict__ inv_deg) {
  int i = blockIdx.x * 256 + threadIdx.x;
  int v = rp[i] + bsum[blockIdx.x];
  rp[i] = v;
  cursor[i] = v;
  inv_deg[i] = 1.0f / (float)(counts[i] + 1);
  if (i == 0) rp[NN] = NE;
}

__global__ void k_fill(const int* __restrict__ src, const int* __restrict__ dst,
                       const int* __restrict__ counts, int* __restrict__ cursor,
                       int* __restrict__ csr_src, float* __restrict__ csr_norm) {
  int e = blockIdx.x * 256 + threadIdx.x;
  if (e >= NE) return;
  int s = src[e], d = dst[e];
  float ds = (float)(counts[s] + 1);
  float dd = (float)(counts[d] + 1);
  int pos = atomicAdd(&cursor[d], 1);
  csr_src[pos] = s;
  csr_norm[pos] = rsqrtf(ds * dd);
}

// ---------------- GCN: t = h @ W + b ----------------
// Classic LDS-tiled GEMM (validated R4: ~28 us/layer, no scratch traffic).
#define HS 68  // hsT row stride (floats): 68*4=272 B, 16B-aligned, breaks pow2 banks
__global__ void __launch_bounds__(256) k_transform(const float* __restrict__ hin,
                                                   const float* __restrict__ W,
                                                   const float* __restrict__ b,
                                                   float* __restrict__ tout) {
  __shared__ float hsT[64 * HS];  // [k][n]  17.4 KB
  __shared__ float Ws[64 * 64];   // [k][c]  16 KB
  int tid = threadIdx.x;
  size_t base = (size_t)blockIdx.x * 64 * 64;

  const float4* h4 = (const float4*)(hin + base);
#pragma unroll
  for (int j = 0; j < 4; j++) {
    int f = tid + 256 * j;        // float4 index within 64x64 tile
    int n = f >> 4, kq = f & 15;  // node row, k-quad
    float4 v = h4[f];
    hsT[(4 * kq + 0) * HS + n] = v.x;
    hsT[(4 * kq + 1) * HS + n] = v.y;
    hsT[(4 * kq + 2) * HS + n] = v.z;
    hsT[(4 * kq + 3) * HS + n] = v.w;
  }
  const float4* w4 = (const float4*)W;
  float4* ws4 = (float4*)Ws;
#pragma unroll
  for (int j = 0; j < 4; j++) ws4[tid + 256 * j] = w4[tid + 256 * j];
  __syncthreads();

  int n0 = (tid >> 4) * 4;  // node quad (16-lane broadcast, free)
  int c0 = (tid & 15) * 4;  // col quad (contiguous 256B, free)
  float acc[4][4];
#pragma unroll
  for (int i = 0; i < 4; i++)
#pragma unroll
    for (int j = 0; j < 4; j++) acc[i][j] = b[c0 + j];

#pragma unroll 4
  for (int k = 0; k < 64; k++) {
    float4 av = *(const float4*)&hsT[k * HS + n0];  // ds_read_b128
    float4 bv = *(const float4*)&Ws[k * 64 + c0];   // ds_read_b128
    acc[0][0] = fmaf(av.x, bv.x, acc[0][0]);
    acc[0][1] = fmaf(av.x, bv.y, acc[0][1]);
    acc[0][2] = fmaf(av.x, bv.z, acc[0][2]);
    acc[0][3] = fmaf(av.x, bv.w, acc[0][3]);
    acc[1][0] = fmaf(av.y, bv.x, acc[1][0]);
    acc[1][1] = fmaf(av.y, bv.y, acc[1][1]);
    acc[1][2] = fmaf(av.y, bv.z, acc[1][2]);
    acc[1][3] = fmaf(av.y, bv.w, acc[1][3]);
    acc[2][0] = fmaf(av.z, bv.x, acc[2][0]);
    acc[2][1] = fmaf(av.z, bv.y, acc[2][1]);
    acc[2][2] = fmaf(av.z, bv.z, acc[2][2]);
    acc[2][3] = fmaf(av.z, bv.w, acc[2][3]);
    acc[3][0] = fmaf(av.w, bv.x, acc[3][0]);
    acc[3][1] = fmaf(av.w, bv.y, acc[3][1]);
    acc[3][2] = fmaf(av.w, bv.z, acc[3][2]);
    acc[3][3] = fmaf(av.w, bv.w, acc[3][3]);
  }

  float4* o4 = (float4*)(tout + base);
#pragma unroll
  for (int i = 0; i < 4; i++) {
    o4[((n0 + i) * 64 + c0) >> 2] =
        make_float4(acc[i][0], acc[i][1], acc[i][2], acc[i][3]);
  }
}

// ---------------- Aggregate: h = relu(sum_{e->n} norm*t[src] + t[n]/deg) ----------------
// Unroll 4 with independent accumulators (validated R5: breaks the
// idx-load -> gather dependent chain; 4 gathers in flight).
__global__ void k_aggregate(const float* __restrict__ t, const int* __restrict__ rp,
                            const int* __restrict__ csr_src, const float* __restrict__ csr_norm,
                            const float* __restrict__ inv_deg, float* __restrict__ hout) {
  int lane = threadIdx.x & 63;
  int n = blockIdx.x * 4 + (threadIdx.x >> 6);
  int beg = rp[n], end = rp[n + 1];
  float a0 = t[(size_t)n * 64 + lane] * inv_deg[n];
  float a1 = 0.f, a2 = 0.f, a3 = 0.f;
  int idx = beg;
  for (; idx + 4 <= end; idx += 4) {
    int s0 = csr_src[idx + 0];
    int s1 = csr_src[idx + 1];
    int s2 = csr_src[idx + 2];
    int s3 = csr_src[idx + 3];
    float w0 = csr_norm[idx + 0];
    float w1 = csr_norm[idx + 1];
    float w2 = csr_norm[idx + 2];
    float w3 = csr_norm[idx + 3];
    a0 = fmaf(w0, t[(size_t)s0 * 64 + lane], a0);
    a1 = fmaf(w1, t[(size_t)s1 * 64 + lane], a1);
    a2 = fmaf(w2, t[(size_t)s2 * 64 + lane], a2);
    a3 = fmaf(w3, t[(size_t)s3 * 64 + lane], a3);
  }
  for (; idx < end; idx++) {
    int s = csr_src[idx];
    float w = csr_norm[idx];
    a0 = fmaf(w, t[(size_t)s * 64 + lane], a0);
  }
  hout[(size_t)n * 64 + lane] = fmaxf((a0 + a1) + (a2 + a3), 0.0f);
}

// ---------------- Readout: graph_ids sorted -> binary-search ranges ----------------
__global__ void k_readout(const float* __restrict__ h, const int* __restrict__ gids,
                          float* __restrict__ r) {
  int lane = threadIdx.x & 63;
  int g = blockIdx.x * 4 + (threadIdx.x >> 6);
  int lo = lowerBound(gids, NN, g);
  int hi = lowerBound(gids, NN, g + 1);
  float acc = 0.f;
  for (int n = lo; n < hi; n++) acc += h[(size_t)n * 64 + lane];
  r[(size_t)g * 64 + lane] = acc;
}

// ---------------- Dense head ----------------
// y1T[j][g] = relu(b1[j] + sum_k concat(r,xa)[g][k] * W1[k][j])
// TRANSPOSED output (g-contiguous rows) so dense2/out can use lane=graph
// coalesced loads with zero LDS. 8 graphs/block; float4 stores (g0 32B-aligned).
__global__ void __launch_bounds__(256) k_dense1(const float* __restrict__ r,
                                                const float* __restrict__ xa,
                                                const float* __restrict__ W1,
                                                const float* __restrict__ b1,
                                                float* __restrict__ y1T) {
  __shared__ float xs[8 * 72];
  int tid = threadIdx.x;
  int g0 = blockIdx.x * 8;
  for (int i = tid; i < 8 * 72; i += 256) {
    int g = i / 72, k = i % 72;
    xs[i] = (k < 64) ? r[(size_t)(g0 + g) * 64 + k] : xa[(size_t)(g0 + g) * 8 + (k - 64)];
  }
  __syncthreads();
  float acc[8][2];
#pragma unroll
  for (int g = 0; g < 8; g++) { acc[g][0] = 0.f; acc[g][1] = 0.f; }
  for (int k = 0; k < 72; k++) {
    float w0 = W1[k * 512 + tid];
    float w1 = W1[k * 512 + 256 + tid];
#pragma unroll
    for (int g = 0; g < 8; g++) {
      float xv = xs[g * 72 + k];  // wave-uniform broadcast
      acc[g][0] = fmaf(xv, w0, acc[g][0]);
      acc[g][1] = fmaf(xv, w1, acc[g][1]);
    }
  }
  float bb0 = b1[tid], bb1 = b1[256 + tid];
  float4 v;
  v = make_float4(fmaxf(acc[0][0] + bb0, 0.f), fmaxf(acc[1][0] + bb0, 0.f),
                  fmaxf(acc[2][0] + bb0, 0.f), fmaxf(acc[3][0] + bb0, 0.f));
  *(float4*)&y1T[(size_t)tid * NG + g0] = v;
  v = make_float4(fmaxf(acc[4][0] + bb0, 0.f), fmaxf(acc[5][0] + bb0, 0.f),
                  fmaxf(acc[6][0] + bb0, 0.f), fmaxf(acc[7][0] + bb0, 0.f));
  *(float4*)&y1T[(size_t)tid * NG + g0 + 4] = v;
  v = make_float4(fmaxf(acc[0][1] + bb1, 0.f), fmaxf(acc[1][1] + bb1, 0.f),
                  fmaxf(acc[2][1] + bb1, 0.f), fmaxf(acc[3][1] + bb1, 0.f));
  *(float4*)&y1T[(size_t)(256 + tid) * NG + g0] = v;
  v = make_float4(fmaxf(acc[4][1] + bb1, 0.f), fmaxf(acc[5][1] + bb1, 0.f),
                  fmaxf(acc[6][1] + bb1, 0.f), fmaxf(acc[7][1] + bb1, 0.f));
  *(float4*)&y1T[(size_t)(256 + tid) * NG + g0 + 4] = v;
}

// y2T = relu(W2^T @ y1T + b2), transposed dataflow: lane = graph.
// R5 dense2 was LDS-BW-bound (1 B/FLOP -> 96 us). Here: ZERO LDS. Per wave:
// 64 g x 16 j; per k one coalesced 256B x-load + block-uniform W2 row chunk
// (j0 from blockIdx only -> s_load) + 16 v_fmac at full lane efficiency.
// x prefetched 2 k ahead. VALU floor ~27 us.
__global__ void __launch_bounds__(256) k_dense2(const float* __restrict__ xT,
                                                const float* __restrict__ W2,
                                                const float* __restrict__ b2,
                                                float* __restrict__ y2T) {
  int tid = threadIdx.x;
  int g  = (blockIdx.x & 31) * 256 + tid;  // 256 consecutive graphs per block
  int j0 = (blockIdx.x >> 5) * 16;         // block-uniform -> W2 reads scalarize
  const float* wp = W2 + j0;
  float acc[16];
#pragma unroll
  for (int u = 0; u < 16; u++) acc[u] = b2[j0 + u];
  float x0 = xT[g];
  float x1 = xT[NG + g];
#pragma unroll 1
  for (int k = 0; k < 512; k += 2) {
    float p0 = x0, p1 = x1;
    if (k + 2 < 512) {
      x0 = xT[(size_t)(k + 2) * NG + g];
      x1 = xT[(size_t)(k + 3) * NG + g];
    }
    const float* w0 = wp + (size_t)k * 512;
    const float* w1 = w0 + 512;
#pragma unroll
    for (int u = 0; u < 16; u++) acc[u] = fmaf(p0, w0[u], acc[u]);
#pragma unroll
    for (int u = 0; u < 16; u++) acc[u] = fmaf(p1, w1[u], acc[u]);
  }
#pragma unroll
  for (int u = 0; u < 16; u++)
    y2T[(size_t)(j0 + u) * NG + g] = fmaxf(acc[u], 0.f);
}

// out[g] = y2T[:,g] . out_W + out_b  -- lane = graph, coalesced, no shuffle
__global__ void k_out(const float* __restrict__ y2T, const float* __restrict__ ow,
                      const float* __restrict__ ob, float* __restrict__ out) {
  int g = blockIdx.x * 256 + threadIdx.x;
  float s0 = 0.f, s1 = 0.f, s2 = 0.f, s3 = 0.f;
#pragma unroll 4
  for (int j = 0; j < 512; j += 4) {
    s0 = fmaf(y2T[(size_t)(j + 0) * NG + g], ow[j + 0], s0);
    s1 = fmaf(y2T[(size_t)(j + 1) * NG + g], ow[j + 1], s1);
    s2 = fmaf(y2T[(size_t)(j + 2) * NG + g], ow[j + 2], s2);
    s3 = fmaf(y2T[(size_t)(j + 3) * NG + g], ow[j + 3], s3);
  }
  out[g] = (s0 + s1) + (s2 + s3) + ob[0];
}

extern "C" void kernel_launch(void* const* d_in, const int* in_sizes, int n_in,
                              void* d_out, int out_size, void* d_ws, size_t ws_size,
                              hipStream_t stream) {
  const float* x_mol    = (const float*)d_in[0];
  const float* x_adduct = (const float*)d_in[1];
  const int*   edge_src = (const int*)d_in[2];
  const int*   edge_dst = (const int*)d_in[3];
  const int*   graph_ids= (const int*)d_in[4];
  const float* gcn_W    = (const float*)d_in[5];
  const float* gcn_b    = (const float*)d_in[6];
  const float* d1W      = (const float*)d_in[7];
  const float* d1b      = (const float*)d_in[8];
  const float* d2W      = (const float*)d_in[9];
  const float* d2b      = (const float*)d_in[10];
  const float* oW       = (const float*)d_in[11];
  const float* obias    = (const float*)d_in[12];
  float* out = (float*)d_out;

  char* p = (char*)d_ws;
  auto alloc = [&](size_t bytes) {
    char* q = p;
    p += (bytes + 255) & ~(size_t)255;
    return q;
  };
  int*   counts   = (int*)alloc((size_t)NN * 4);
  int*   rp       = (int*)alloc((size_t)(NN + 1) * 4);
  int*   cursor   = (int*)alloc((size_t)NN * 4);
  int*   bsum     = (int*)alloc(1024 * 4);
  float* inv_deg  = (float*)alloc((size_t)NN * 4);
  int*   csr_src  = (int*)alloc((size_t)NE * 4);
  float* csr_norm = (float*)alloc((size_t)NE * 4);
  float* t        = (float*)alloc((size_t)NN * 64 * 4);
  float* h        = (float*)alloc((size_t)NN * 64 * 4);
  float* r        = (float*)alloc((size_t)NG * 64 * 4);
  float* y1T      = (float*)alloc((size_t)NG * 512 * 4);
  float* y2T      = (float*)alloc((size_t)NG * 512 * 4);

  hipMemsetAsync(counts, 0, (size_t)NN * 4, stream);
  k_count<<<NE / 256, 256, 0, stream>>>(edge_dst, counts);
  k_scan1<<<NN / 256, 256, 0, stream>>>(counts, rp, bsum);
  k_scan2<<<1, 1024, 0, stream>>>(bsum);
  k_scan3<<<NN / 256, 256, 0, stream>>>(counts, rp, bsum, cursor, inv_deg);
  k_fill<<<NE / 256, 256, 0, stream>>>(edge_src, edge_dst, counts, cursor, csr_src, csr_norm);

  const float* hin = x_mol;
  for (int L = 0; L < 3; L++) {
    k_transform<<<NN / 64, 256, 0, stream>>>(hin, gcn_W + (size_t)L * 64 * 64,
                                             gcn_b + (size_t)L * 64, t);
    k_aggregate<<<NN / 4, 256, 0, stream>>>(t, rp, csr_src, csr_norm, inv_deg, h);
    hin = h;
  }
  k_readout<<<NG / 4, 256, 0, stream>>>(h, graph_ids, r);
  k_dense1<<<NG / 8, 256, 0, stream>>>(r, x_adduct, d1W, d1b, y1T);
  k_dense2<<<1024, 256, 0, stream>>>(y1T, d2W, d2b, y2T);
  k_out<<<NG / 256, 256, 0, stream>>>(y2T, oW, obias, out);
}

// Round 7
// 738.186 us; speedup vs baseline: 1.0383x; 1.0383x over previous
//
#include <hip/hip_runtime.h>

#define NN 262144   // nodes
#define NE 1048576  // edges
#define NG 8192     // graphs
#define FD 64       // feature dim
#define AD 8        // adduct dim
#define DN 512      // dense dim

__device__ __forceinline__ int lowerBound(const int* __restrict__ a, int n, int v) {
  int lo = 0, hi = n;
  while (lo < hi) { int mid = (lo + hi) >> 1; if (a[mid] < v) lo = mid + 1; else hi = mid; }
  return lo;
}

// ---------------- CSR build ----------------
__global__ void k_count(const int* __restrict__ dst, int* __restrict__ counts) {
  int e = blockIdx.x * 256 + threadIdx.x;
  if (e < NE) atomicAdd(&counts[dst[e]], 1);
}

__global__ void k_scan1(const int* __restrict__ counts, int* __restrict__ rp,
                        int* __restrict__ bsum) {
  __shared__ int s[256];
  int tid = threadIdx.x;
  int i = blockIdx.x * 256 + tid;
  int orig = counts[i];
  s[tid] = orig;
  __syncthreads();
  for (int off = 1; off < 256; off <<= 1) {
    int v = (tid >= off) ? s[tid - off] : 0;
    __syncthreads();
    s[tid] += v;
    __syncthreads();
  }
  rp[i] = s[tid] - orig;  // block-local exclusive scan
  if (tid == 255) bsum[blockIdx.x] = s[tid];
}

__global__ void k_scan2(int* __restrict__ bsum) {
  __shared__ int s[1024];
  int tid = threadIdx.x;
  int orig = bsum[tid];
  s[tid] = orig;
  __syncthreads();
  for (int off = 1; off < 1024; off <<= 1) {
    int v = (tid >= off) ? s[tid - off] : 0;
    __syncthreads();
    s[tid] += v;
    __syncthreads();
  }
  bsum[tid] = s[tid] - orig;  // exclusive
}

__global__ void k_scan3(const int* __restrict__ counts, int* __restrict__ rp,
                        const int* __restrict__ bsum, int* __restrict__ cursor,
                        float* __restrict__ inv_deg) {
  int i = blockIdx.x * 256 + threadIdx.x;
  int v = rp[i] + bsum[blockIdx.x];
  rp[i] = v;
  cursor[i] = v;
  inv_deg[i] = 1.0f / (float)(counts[i] + 1);
  if (i == 0) rp[NN] = NE;
}

__global__ void k_fill(const int* __restrict__ src, const int* __restrict__ dst,
                       const int* __restrict__ counts, int* __restrict__ cursor,
                       int* __restrict__ csr_src, float* __restrict__ csr_norm) {
  int e = blockIdx.x * 256 + threadIdx.x;
  if (e >= NE) return;
  int s = src[e], d = dst[e];
  float ds = (float)(counts[s] + 1);
  float dd = (float)(counts[d] + 1);
  int pos = atomicAdd(&cursor[d], 1);
  csr_src[pos] = s;
  csr_norm[pos] = rsqrtf(ds * dd);
}

// ---------------- GCN: t = h @ W + b ----------------
// Classic LDS-tiled GEMM (validated R4: ~28 us/layer, no scratch traffic).
#define HS 68  // hsT row stride (floats): 68*4=272 B, 16B-aligned, breaks pow2 banks
__global__ void __launch_bounds__(256) k_transform(const float* __restrict__ hin,
                                                   const float* __restrict__ W,
                                                   const float* __restrict__ b,
                                                   float* __restrict__ tout) {
  __shared__ float hsT[64 * HS];  // [k][n]  17.4 KB
  __shared__ float Ws[64 * 64];   // [k][c]  16 KB
  int tid = threadIdx.x;
  size_t base = (size_t)blockIdx.x * 64 * 64;

  const float4* h4 = (const float4*)(hin + base);
#pragma unroll
  for (int j = 0; j < 4; j++) {
    int f = tid + 256 * j;        // float4 index within 64x64 tile
    int n = f >> 4, kq = f & 15;  // node row, k-quad
    float4 v = h4[f];
    hsT[(4 * kq + 0) * HS + n] = v.x;
    hsT[(4 * kq + 1) * HS + n] = v.y;
    hsT[(4 * kq + 2) * HS + n] = v.z;
    hsT[(4 * kq + 3) * HS + n] = v.w;
  }
  const float4* w4 = (const float4*)W;
  float4* ws4 = (float4*)Ws;
#pragma unroll
  for (int j = 0; j < 4; j++) ws4[tid + 256 * j] = w4[tid + 256 * j];
  __syncthreads();

  int n0 = (tid >> 4) * 4;  // node quad (16-lane broadcast, free)
  int c0 = (tid & 15) * 4;  // col quad (contiguous 256B, free)
  float acc[4][4];
#pragma unroll
  for (int i = 0; i < 4; i++)
#pragma unroll
    for (int j = 0; j < 4; j++) acc[i][j] = b[c0 + j];

#pragma unroll 4
  for (int k = 0; k < 64; k++) {
    float4 av = *(const float4*)&hsT[k * HS + n0];  // ds_read_b128
    float4 bv = *(const float4*)&Ws[k * 64 + c0];   // ds_read_b128
    acc[0][0] = fmaf(av.x, bv.x, acc[0][0]);
    acc[0][1] = fmaf(av.x, bv.y, acc[0][1]);
    acc[0][2] = fmaf(av.x, bv.z, acc[0][2]);
    acc[0][3] = fmaf(av.x, bv.w, acc[0][3]);
    acc[1][0] = fmaf(av.y, bv.x, acc[1][0]);
    acc[1][1] = fmaf(av.y, bv.y, acc[1][1]);
    acc[1][2] = fmaf(av.y, bv.z, acc[1][2]);
    acc[1][3] = fmaf(av.y, bv.w, acc[1][3]);
    acc[2][0] = fmaf(av.z, bv.x, acc[2][0]);
    acc[2][1] = fmaf(av.z, bv.y, acc[2][1]);
    acc[2][2] = fmaf(av.z, bv.z, acc[2][2]);
    acc[2][3] = fmaf(av.z, bv.w, acc[2][3]);
    acc[3][0] = fmaf(av.w, bv.x, acc[3][0]);
    acc[3][1] = fmaf(av.w, bv.y, acc[3][1]);
    acc[3][2] = fmaf(av.w, bv.z, acc[3][2]);
    acc[3][3] = fmaf(av.w, bv.w, acc[3][3]);
  }

  float4* o4 = (float4*)(tout + base);
#pragma unroll
  for (int i = 0; i < 4; i++) {
    o4[((n0 + i) * 64 + c0) >> 2] =
        make_float4(acc[i][0], acc[i][1], acc[i][2], acc[i][3]);
  }
}

// ---------------- Aggregate: h = relu(sum_{e->n} norm*t[src] + t[n]/deg) ----------------
// Unroll 4 with independent accumulators (validated R5: breaks the
// idx-load -> gather dependent chain; 4 gathers in flight).
__global__ void k_aggregate(const float* __restrict__ t, const int* __restrict__ rp,
                            const int* __restrict__ csr_src, const float* __restrict__ csr_norm,
                            const float* __restrict__ inv_deg, float* __restrict__ hout) {
  int lane = threadIdx.x & 63;
  int n = blockIdx.x * 4 + (threadIdx.x >> 6);
  int beg = rp[n], end = rp[n + 1];
  float a0 = t[(size_t)n * 64 + lane] * inv_deg[n];
  float a1 = 0.f, a2 = 0.f, a3 = 0.f;
  int idx = beg;
  for (; idx + 4 <= end; idx += 4) {
    int s0 = csr_src[idx + 0];
    int s1 = csr_src[idx + 1];
    int s2 = csr_src[idx + 2];
    int s3 = csr_src[idx + 3];
    float w0 = csr_norm[idx + 0];
    float w1 = csr_norm[idx + 1];
    float w2 = csr_norm[idx + 2];
    float w3 = csr_norm[idx + 3];
    a0 = fmaf(w0, t[(size_t)s0 * 64 + lane], a0);
    a1 = fmaf(w1, t[(size_t)s1 * 64 + lane], a1);
    a2 = fmaf(w2, t[(size_t)s2 * 64 + lane], a2);
    a3 = fmaf(w3, t[(size_t)s3 * 64 + lane], a3);
  }
  for (; idx < end; idx++) {
    int s = csr_src[idx];
    float w = csr_norm[idx];
    a0 = fmaf(w, t[(size_t)s * 64 + lane], a0);
  }
  hout[(size_t)n * 64 + lane] = fmaxf((a0 + a1) + (a2 + a3), 0.0f);
}

// ---------------- Readout: graph_ids sorted -> binary-search ranges ----------------
__global__ void k_readout(const float* __restrict__ h, const int* __restrict__ gids,
                          float* __restrict__ r) {
  int lane = threadIdx.x & 63;
  int g = blockIdx.x * 4 + (threadIdx.x >> 6);
  int lo = lowerBound(gids, NN, g);
  int hi = lowerBound(gids, NN, g + 1);
  float acc = 0.f;
  for (int n = lo; n < hi; n++) acc += h[(size_t)n * 64 + lane];
  r[(size_t)g * 64 + lane] = acc;
}

// ---------------- Dense head ----------------
// y1T[j][g] = relu(b1[j] + sum_k concat(r,xa)[g][k] * W1[k][j])
// TRANSPOSED output (g-contiguous rows) so dense2/out use lane=graph coalesced.
__global__ void __launch_bounds__(256) k_dense1(const float* __restrict__ r,
                                                const float* __restrict__ xa,
                                                const float* __restrict__ W1,
                                                const float* __restrict__ b1,
                                                float* __restrict__ y1T) {
  __shared__ float xs[8 * 72];
  int tid = threadIdx.x;
  int g0 = blockIdx.x * 8;
  for (int i = tid; i < 8 * 72; i += 256) {
    int g = i / 72, k = i % 72;
    xs[i] = (k < 64) ? r[(size_t)(g0 + g) * 64 + k] : xa[(size_t)(g0 + g) * 8 + (k - 64)];
  }
  __syncthreads();
  float acc[8][2];
#pragma unroll
  for (int g = 0; g < 8; g++) { acc[g][0] = 0.f; acc[g][1] = 0.f; }
  for (int k = 0; k < 72; k++) {
    float w0 = W1[k * 512 + tid];
    float w1 = W1[k * 512 + 256 + tid];
#pragma unroll
    for (int g = 0; g < 8; g++) {
      float xv = xs[g * 72 + k];  // wave-uniform broadcast
      acc[g][0] = fmaf(xv, w0, acc[g][0]);
      acc[g][1] = fmaf(xv, w1, acc[g][1]);
    }
  }
  float bb0 = b1[tid], bb1 = b1[256 + tid];
  float4 v;
  v = make_float4(fmaxf(acc[0][0] + bb0, 0.f), fmaxf(acc[1][0] + bb0, 0.f),
                  fmaxf(acc[2][0] + bb0, 0.f), fmaxf(acc[3][0] + bb0, 0.f));
  *(float4*)&y1T[(size_t)tid * NG + g0] = v;
  v = make_float4(fmaxf(acc[4][0] + bb0, 0.f), fmaxf(acc[5][0] + bb0, 0.f),
                  fmaxf(acc[6][0] + bb0, 0.f), fmaxf(acc[7][0] + bb0, 0.f));
  *(float4*)&y1T[(size_t)tid * NG + g0 + 4] = v;
  v = make_float4(fmaxf(acc[0][1] + bb1, 0.f), fmaxf(acc[1][1] + bb1, 0.f),
                  fmaxf(acc[2][1] + bb1, 0.f), fmaxf(acc[3][1] + bb1, 0.f));
  *(float4*)&y1T[(size_t)(256 + tid) * NG + g0] = v;
  v = make_float4(fmaxf(acc[4][1] + bb1, 0.f), fmaxf(acc[5][1] + bb1, 0.f),
                  fmaxf(acc[6][1] + bb1, 0.f), fmaxf(acc[7][1] + bb1, 0.f));
  *(float4*)&y1T[(size_t)(256 + tid) * NG + g0 + 4] = v;
}

// y2T = relu(W2^T @ y1T + b2), lane = graph. R6 scalar-W2 version stalled on
// the s_load chain (s_waitcnt lgkmcnt per iter, not pipelineable). Now: W2
// slice (512k x 16j = 32 KB) staged in LDS, read via wave-uniform
// ds_read_b128 BROADCASTS (16 B moved, conflict-free, fine-grained lgkmcnt).
// x stays coalesced-global, prefetched 4 ahead. VALU floor ~27 us.
__global__ void __launch_bounds__(256) k_dense2(const float* __restrict__ xT,
                                                const float* __restrict__ W2,
                                                const float* __restrict__ b2,
                                                float* __restrict__ y2T) {
  __shared__ float ws[512 * 16];  // [k][j-slice] 32 KB
  int tid = threadIdx.x;
  int g  = (blockIdx.x & 31) * 256 + tid;  // 256 consecutive graphs
  int j0 = (blockIdx.x >> 5) * 16;
  {
    int u = tid & 15, kb = tid >> 4;  // 16 k-rows per sweep
#pragma unroll
    for (int i = 0; i < 32; i++) {
      int k = kb + 16 * i;
      ws[k * 16 + u] = W2[(size_t)k * 512 + j0 + u];  // 64B segs, coalesced per 16 lanes
    }
  }
  float acc[16];
#pragma unroll
  for (int u = 0; u < 16; u++) acc[u] = b2[j0 + u];
  __syncthreads();

  float x0 = xT[g];
  float x1 = xT[(size_t)1 * NG + g];
  float x2 = xT[(size_t)2 * NG + g];
  float x3 = xT[(size_t)3 * NG + g];
#pragma unroll 1
  for (int k = 0; k < 512; k += 4) {
    float p0 = x0, p1 = x1, p2 = x2, p3 = x3;
    if (k + 4 < 512) {
      x0 = xT[(size_t)(k + 4) * NG + g];
      x1 = xT[(size_t)(k + 5) * NG + g];
      x2 = xT[(size_t)(k + 6) * NG + g];
      x3 = xT[(size_t)(k + 7) * NG + g];
    }
#pragma unroll
    for (int kk = 0; kk < 4; kk++) {
      float p = (kk == 0) ? p0 : (kk == 1) ? p1 : (kk == 2) ? p2 : p3;
      const float4 wa = *(const float4*)&ws[(k + kk) * 16 + 0];   // broadcast b128
      const float4 wb = *(const float4*)&ws[(k + kk) * 16 + 4];
      const float4 wc = *(const float4*)&ws[(k + kk) * 16 + 8];
      const float4 wd = *(const float4*)&ws[(k + kk) * 16 + 12];
      acc[0]  = fmaf(p, wa.x, acc[0]);
      acc[1]  = fmaf(p, wa.y, acc[1]);
      acc[2]  = fmaf(p, wa.z, acc[2]);
      acc[3]  = fmaf(p, wa.w, acc[3]);
      acc[4]  = fmaf(p, wb.x, acc[4]);
      acc[5]  = fmaf(p, wb.y, acc[5]);
      acc[6]  = fmaf(p, wb.z, acc[6]);
      acc[7]  = fmaf(p, wb.w, acc[7]);
      acc[8]  = fmaf(p, wc.x, acc[8]);
      acc[9]  = fmaf(p, wc.y, acc[9]);
      acc[10] = fmaf(p, wc.z, acc[10]);
      acc[11] = fmaf(p, wc.w, acc[11]);
      acc[12] = fmaf(p, wd.x, acc[12]);
      acc[13] = fmaf(p, wd.y, acc[13]);
      acc[14] = fmaf(p, wd.z, acc[14]);
      acc[15] = fmaf(p, wd.w, acc[15]);
    }
  }
#pragma unroll
  for (int u = 0; u < 16; u++)
    y2T[(size_t)(j0 + u) * NG + g] = fmaxf(acc[u], 0.f);
}

// out[g] = y2T[:,g] . out_W + out_b  -- lane = graph, coalesced, no shuffle
__global__ void k_out(const float* __restrict__ y2T, const float* __restrict__ ow,
                      const float* __restrict__ ob, float* __restrict__ out) {
  int g = blockIdx.x * 256 + threadIdx.x;
  float s0 = 0.f, s1 = 0.f, s2 = 0.f, s3 = 0.f;
#pragma unroll 4
  for (int j = 0; j < 512; j += 4) {
    s0 = fmaf(y2T[(size_t)(j + 0) * NG + g], ow[j + 0], s0);
    s1 = fmaf(y2T[(size_t)(j + 1) * NG + g], ow[j + 1], s1);
    s2 = fmaf(y2T[(size_t)(j + 2) * NG + g], ow[j + 2], s2);
    s3 = fmaf(y2T[(size_t)(j + 3) * NG + g], ow[j + 3], s3);
  }
  out[g] = (s0 + s1) + (s2 + s3) + ob[0];
}

extern "C" void kernel_launch(void* const* d_in, const int* in_sizes, int n_in,
                              void* d_out, int out_size, void* d_ws, size_t ws_size,
                              hipStream_t stream) {
  const float* x_mol    = (const float*)d_in[0];
  const float* x_adduct = (const float*)d_in[1];
  const int*   edge_src = (const int*)d_in[2];
  const int*   edge_dst = (const int*)d_in[3];
  const int*   graph_ids= (const int*)d_in[4];
  const float* gcn_W    = (const float*)d_in[5];
  const float* gcn_b    = (const float*)d_in[6];
  const float* d1W      = (const float*)d_in[7];
  const float* d1b      = (const float*)d_in[8];
  const float* d2W      = (const float*)d_in[9];
  const float* d2b      = (const float*)d_in[10];
  const float* oW       = (const float*)d_in[11];
  const float* obias    = (const float*)d_in[12];
  float* out = (float*)d_out;

  char* p = (char*)d_ws;
  auto alloc = [&](size_t bytes) {
    char* q = p;
    p += (bytes + 255) & ~(size_t)255;
    return q;
  };
  int*   counts   = (int*)alloc((size_t)NN * 4);
  int*   rp       = (int*)alloc((size_t)(NN + 1) * 4);
  int*   cursor   = (int*)alloc((size_t)NN * 4);
  int*   bsum     = (int*)alloc(1024 * 4);
  float* inv_deg  = (float*)alloc((size_t)NN * 4);
  int*   csr_src  = (int*)alloc((size_t)NE * 4);
  float* csr_norm = (float*)alloc((size_t)NE * 4);
  float* t        = (float*)alloc((size_t)NN * 64 * 4);
  float* h        = (float*)alloc((size_t)NN * 64 * 4);
  float* r        = (float*)alloc((size_t)NG * 64 * 4);
  float* y1T      = (float*)alloc((size_t)NG * 512 * 4);
  float* y2T      = (float*)alloc((size_t)NG * 512 * 4);

  hipMemsetAsync(counts, 0, (size_t)NN * 4, stream);
  k_count<<<NE / 256, 256, 0, stream>>>(edge_dst, counts);
  k_scan1<<<NN / 256, 256, 0, stream>>>(counts, rp, bsum);
  k_scan2<<<1, 1024, 0, stream>>>(bsum);
  k_scan3<<<NN / 256, 256, 0, stream>>>(counts, rp, bsum, cursor, inv_deg);
  k_fill<<<NE / 256, 256, 0, stream>>>(edge_src, edge_dst, counts, cursor, csr_src, csr_norm);

  const float* hin = x_mol;
  for (int L = 0; L < 3; L++) {
    k_transform<<<NN / 64, 256, 0, stream>>>(hin, gcn_W + (size_t)L * 64 * 64,
                                             gcn_b + (size_t)L * 64, t);
    k_aggregate<<<NN / 4, 256, 0, stream>>>(t, rp, csr_src, csr_norm, inv_deg, h);
    hin = h;
  }
  k_readout<<<NG / 4, 256, 0, stream>>>(h, graph_ids, r);
  k_dense1<<<NG / 8, 256, 0, stream>>>(r, x_adduct, d1W, d1b, y1T);
  k_dense2<<<1024, 256, 0, stream>>>(y1T, d2W, d2b, y2T);
  k_out<<<NG / 256, 256, 0, stream>>>(y2T, oW, obias, out);
}

// Round 8
// 715.280 us; speedup vs baseline: 1.0716x; 1.0320x over previous
//
#include <hip/hip_runtime.h>

#define NN 262144   // nodes
#define NE 1048576  // edges
#define NG 8192     // graphs
#define FD 64       // feature dim
#define AD 8        // adduct dim
#define DN 512      // dense dim

__device__ __forceinline__ int lowerBound(const int* __restrict__ a, int n, int v) {
  int lo = 0, hi = n;
  while (lo < hi) { int mid = (lo + hi) >> 1; if (a[mid] < v) lo = mid + 1; else hi = mid; }
  return lo;
}

// ---------------- CSR build ----------------
__global__ void k_count(const int* __restrict__ dst, int* __restrict__ counts) {
  int e = blockIdx.x * 256 + threadIdx.x;
  if (e < NE) atomicAdd(&counts[dst[e]], 1);
}

__global__ void k_scan1(const int* __restrict__ counts, int* __restrict__ rp,
                        int* __restrict__ bsum) {
  __shared__ int s[256];
  int tid = threadIdx.x;
  int i = blockIdx.x * 256 + tid;
  int orig = counts[i];
  s[tid] = orig;
  __syncthreads();
  for (int off = 1; off < 256; off <<= 1) {
    int v = (tid >= off) ? s[tid - off] : 0;
    __syncthreads();
    s[tid] += v;
    __syncthreads();
  }
  rp[i] = s[tid] - orig;  // block-local exclusive scan
  if (tid == 255) bsum[blockIdx.x] = s[tid];
}

__global__ void k_scan2(int* __restrict__ bsum) {
  __shared__ int s[1024];
  int tid = threadIdx.x;
  int orig = bsum[tid];
  s[tid] = orig;
  __syncthreads();
  for (int off = 1; off < 1024; off <<= 1) {
    int v = (tid >= off) ? s[tid - off] : 0;
    __syncthreads();
    s[tid] += v;
    __syncthreads();
  }
  bsum[tid] = s[tid] - orig;  // exclusive
}

__global__ void k_scan3(const int* __restrict__ counts, int* __restrict__ rp,
                        const int* __restrict__ bsum, int* __restrict__ cursor,
                        float* __restrict__ inv_deg) {
  int i = blockIdx.x * 256 + threadIdx.x;
  int v = rp[i] + bsum[blockIdx.x];
  rp[i] = v;
  cursor[i] = v;
  inv_deg[i] = 1.0f / (float)(counts[i] + 1);
  if (i == 0) rp[NN] = NE;
}

__global__ void k_fill(const int* __restrict__ src, const int* __restrict__ dst,
                       const int* __restrict__ counts, int* __restrict__ cursor,
                       int* __restrict__ csr_src, float* __restrict__ csr_norm) {
  int e = blockIdx.x * 256 + threadIdx.x;
  if (e >= NE) return;
  int s = src[e], d = dst[e];
  float ds = (float)(counts[s] + 1);
  float dd = (float)(counts[d] + 1);
  int pos = atomicAdd(&cursor[d], 1);
  csr_src[pos] = s;
  csr_norm[pos] = rsqrtf(ds * dd);
}

// ---------------- GCN: t = h @ W + b ----------------
// Classic LDS-tiled GEMM (validated R4: ~28 us/layer, no scratch traffic).
#define HS 68  // hsT row stride (floats): 68*4=272 B, 16B-aligned, breaks pow2 banks
__global__ void __launch_bounds__(256) k_transform(const float* __restrict__ hin,
                                                   const float* __restrict__ W,
                                                   const float* __restrict__ b,
                                                   float* __restrict__ tout) {
  __shared__ float hsT[64 * HS];  // [k][n]  17.4 KB
  __shared__ float Ws[64 * 64];   // [k][c]  16 KB
  int tid = threadIdx.x;
  size_t base = (size_t)blockIdx.x * 64 * 64;

  const float4* h4 = (const float4*)(hin + base);
#pragma unroll
  for (int j = 0; j < 4; j++) {
    int f = tid + 256 * j;        // float4 index within 64x64 tile
    int n = f >> 4, kq = f & 15;  // node row, k-quad
    float4 v = h4[f];
    hsT[(4 * kq + 0) * HS + n] = v.x;
    hsT[(4 * kq + 1) * HS + n] = v.y;
    hsT[(4 * kq + 2) * HS + n] = v.z;
    hsT[(4 * kq + 3) * HS + n] = v.w;
  }
  const float4* w4 = (const float4*)W;
  float4* ws4 = (float4*)Ws;
#pragma unroll
  for (int j = 0; j < 4; j++) ws4[tid + 256 * j] = w4[tid + 256 * j];
  __syncthreads();

  int n0 = (tid >> 4) * 4;  // node quad (16-lane broadcast, free)
  int c0 = (tid & 15) * 4;  // col quad (contiguous 256B, free)
  float acc[4][4];
#pragma unroll
  for (int i = 0; i < 4; i++)
#pragma unroll
    for (int j = 0; j < 4; j++) acc[i][j] = b[c0 + j];

#pragma unroll 4
  for (int k = 0; k < 64; k++) {
    float4 av = *(const float4*)&hsT[k * HS + n0];  // ds_read_b128
    float4 bv = *(const float4*)&Ws[k * 64 + c0];   // ds_read_b128
    acc[0][0] = fmaf(av.x, bv.x, acc[0][0]);
    acc[0][1] = fmaf(av.x, bv.y, acc[0][1]);
    acc[0][2] = fmaf(av.x, bv.z, acc[0][2]);
    acc[0][3] = fmaf(av.x, bv.w, acc[0][3]);
    acc[1][0] = fmaf(av.y, bv.x, acc[1][0]);
    acc[1][1] = fmaf(av.y, bv.y, acc[1][1]);
    acc[1][2] = fmaf(av.y, bv.z, acc[1][2]);
    acc[1][3] = fmaf(av.y, bv.w, acc[1][3]);
    acc[2][0] = fmaf(av.z, bv.x, acc[2][0]);
    acc[2][1] = fmaf(av.z, bv.y, acc[2][1]);
    acc[2][2] = fmaf(av.z, bv.z, acc[2][2]);
    acc[2][3] = fmaf(av.z, bv.w, acc[2][3]);
    acc[3][0] = fmaf(av.w, bv.x, acc[3][0]);
    acc[3][1] = fmaf(av.w, bv.y, acc[3][1]);
    acc[3][2] = fmaf(av.w, bv.z, acc[3][2]);
    acc[3][3] = fmaf(av.w, bv.w, acc[3][3]);
  }

  float4* o4 = (float4*)(tout + base);
#pragma unroll
  for (int i = 0; i < 4; i++) {
    o4[((n0 + i) * 64 + c0) >> 2] =
        make_float4(acc[i][0], acc[i][1], acc[i][2], acc[i][3]);
  }
}

// ---------------- Aggregate: h = relu(sum_{e->n} norm*t[src] + t[n]/deg) ----------------
// Unroll 4 with independent accumulators (validated R5: breaks the
// idx-load -> gather dependent chain; 4 gathers in flight).
__global__ void k_aggregate(const float* __restrict__ t, const int* __restrict__ rp,
                            const int* __restrict__ csr_src, const float* __restrict__ csr_norm,
                            const float* __restrict__ inv_deg, float* __restrict__ hout) {
  int lane = threadIdx.x & 63;
  int n = blockIdx.x * 4 + (threadIdx.x >> 6);
  int beg = rp[n], end = rp[n + 1];
  float a0 = t[(size_t)n * 64 + lane] * inv_deg[n];
  float a1 = 0.f, a2 = 0.f, a3 = 0.f;
  int idx = beg;
  for (; idx + 4 <= end; idx += 4) {
    int s0 = csr_src[idx + 0];
    int s1 = csr_src[idx + 1];
    int s2 = csr_src[idx + 2];
    int s3 = csr_src[idx + 3];
    float w0 = csr_norm[idx + 0];
    float w1 = csr_norm[idx + 1];
    float w2 = csr_norm[idx + 2];
    float w3 = csr_norm[idx + 3];
    a0 = fmaf(w0, t[(size_t)s0 * 64 + lane], a0);
    a1 = fmaf(w1, t[(size_t)s1 * 64 + lane], a1);
    a2 = fmaf(w2, t[(size_t)s2 * 64 + lane], a2);
    a3 = fmaf(w3, t[(size_t)s3 * 64 + lane], a3);
  }
  for (; idx < end; idx++) {
    int s = csr_src[idx];
    float w = csr_norm[idx];
    a0 = fmaf(w, t[(size_t)s * 64 + lane], a0);
  }
  hout[(size_t)n * 64 + lane] = fmaxf((a0 + a1) + (a2 + a3), 0.0f);
}

// ---------------- Readout: graph_ids sorted -> binary-search ranges ----------------
__global__ void k_readout(const float* __restrict__ h, const int* __restrict__ gids,
                          float* __restrict__ r) {
  int lane = threadIdx.x & 63;
  int g = blockIdx.x * 4 + (threadIdx.x >> 6);
  int lo = lowerBound(gids, NN, g);
  int hi = lowerBound(gids, NN, g + 1);
  float acc = 0.f;
  for (int n = lo; n < hi; n++) acc += h[(size_t)n * 64 + lane];
  r[(size_t)g * 64 + lane] = acc;
}

// ---------------- Dense head ----------------
// y1T[j][g] = relu(b1[j] + sum_k concat(r,xa)[g][k] * W1[k][j])
// TRANSPOSED output (g-contiguous rows) so dense2/out use lane=graph coalesced.
__global__ void __launch_bounds__(256) k_dense1(const float* __restrict__ r,
                                                const float* __restrict__ xa,
                                                const float* __restrict__ W1,
                                                const float* __restrict__ b1,
                                                float* __restrict__ y1T) {
  __shared__ float xs[8 * 72];
  int tid = threadIdx.x;
  int g0 = blockIdx.x * 8;
  for (int i = tid; i < 8 * 72; i += 256) {
    int g = i / 72, k = i % 72;
    xs[i] = (k < 64) ? r[(size_t)(g0 + g) * 64 + k] : xa[(size_t)(g0 + g) * 8 + (k - 64)];
  }
  __syncthreads();
  float acc[8][2];
#pragma unroll
  for (int g = 0; g < 8; g++) { acc[g][0] = 0.f; acc[g][1] = 0.f; }
  for (int k = 0; k < 72; k++) {
    float w0 = W1[k * 512 + tid];
    float w1 = W1[k * 512 + 256 + tid];
#pragma unroll
    for (int g = 0; g < 8; g++) {
      float xv = xs[g * 72 + k];  // wave-uniform broadcast
      acc[g][0] = fmaf(xv, w0, acc[g][0]);
      acc[g][1] = fmaf(xv, w1, acc[g][1]);
    }
  }
  float bb0 = b1[tid], bb1 = b1[256 + tid];
  float4 v;
  v = make_float4(fmaxf(acc[0][0] + bb0, 0.f), fmaxf(acc[1][0] + bb0, 0.f),
                  fmaxf(acc[2][0] + bb0, 0.f), fmaxf(acc[3][0] + bb0, 0.f));
  *(float4*)&y1T[(size_t)tid * NG + g0] = v;
  v = make_float4(fmaxf(acc[4][0] + bb0, 0.f), fmaxf(acc[5][0] + bb0, 0.f),
                  fmaxf(acc[6][0] + bb0, 0.f), fmaxf(acc[7][0] + bb0, 0.f));
  *(float4*)&y1T[(size_t)tid * NG + g0 + 4] = v;
  v = make_float4(fmaxf(acc[0][1] + bb1, 0.f), fmaxf(acc[1][1] + bb1, 0.f),
                  fmaxf(acc[2][1] + bb1, 0.f), fmaxf(acc[3][1] + bb1, 0.f));
  *(float4*)&y1T[(size_t)(256 + tid) * NG + g0] = v;
  v = make_float4(fmaxf(acc[4][1] + bb1, 0.f), fmaxf(acc[5][1] + bb1, 0.f),
                  fmaxf(acc[6][1] + bb1, 0.f), fmaxf(acc[7][1] + bb1, 0.f));
  *(float4*)&y1T[(size_t)(256 + tid) * NG + g0 + 4] = v;
}

// y2T = relu(W2^T @ y1T + b2), lane = graph, W2 slice in LDS (R7).
// R7 stalled at VALUBusy 47%: fma:ds_read = 4:1 too low. Now each thread
// processes TWO graphs (g, g+256) against the same 16-j W slice: per k,
// 4 ds_read_b128 + 32 fma (8:1) -> VALU-bound. 512 blocks = 16 gb x 32 jb.
__global__ void __launch_bounds__(256) k_dense2(const float* __restrict__ xT,
                                                const float* __restrict__ W2,
                                                const float* __restrict__ b2,
                                                float* __restrict__ y2T) {
  __shared__ float ws[512 * 16];  // [k][j-slice] 32 KB
  int tid = threadIdx.x;
  int gA = (blockIdx.x & 15) * 512 + tid;  // graphs [gb*512 .. gb*512+512)
  int gB = gA + 256;
  int j0 = (blockIdx.x >> 4) * 16;
  {
    int u = tid & 15, kb = tid >> 4;  // 16 k-rows per sweep
#pragma unroll
    for (int i = 0; i < 32; i++) {
      int k = kb + 16 * i;
      ws[k * 16 + u] = W2[(size_t)k * 512 + j0 + u];  // 64B segs, coalesced per 16 lanes
    }
  }
  float accA[16], accB[16];
#pragma unroll
  for (int u = 0; u < 16; u++) { float bb = b2[j0 + u]; accA[u] = bb; accB[u] = bb; }
  __syncthreads();

  float pa0 = xT[gA];
  float pa1 = xT[(size_t)1 * NG + gA];
  float pa2 = xT[(size_t)2 * NG + gA];
  float pa3 = xT[(size_t)3 * NG + gA];
  float pb0 = xT[gB];
  float pb1 = xT[(size_t)1 * NG + gB];
  float pb2 = xT[(size_t)2 * NG + gB];
  float pb3 = xT[(size_t)3 * NG + gB];
#pragma unroll 1
  for (int k = 0; k < 512; k += 4) {
    float a0 = pa0, a1 = pa1, a2 = pa2, a3 = pa3;
    float b0 = pb0, b1 = pb1, b2v = pb2, b3 = pb3;
    if (k + 4 < 512) {
      pa0 = xT[(size_t)(k + 4) * NG + gA];
      pa1 = xT[(size_t)(k + 5) * NG + gA];
      pa2 = xT[(size_t)(k + 6) * NG + gA];
      pa3 = xT[(size_t)(k + 7) * NG + gA];
      pb0 = xT[(size_t)(k + 4) * NG + gB];
      pb1 = xT[(size_t)(k + 5) * NG + gB];
      pb2 = xT[(size_t)(k + 6) * NG + gB];
      pb3 = xT[(size_t)(k + 7) * NG + gB];
    }
#pragma unroll
    for (int kk = 0; kk < 4; kk++) {
      float pA = (kk == 0) ? a0 : (kk == 1) ? a1 : (kk == 2) ? a2 : a3;
      float pB = (kk == 0) ? b0 : (kk == 1) ? b1 : (kk == 2) ? b2v : b3;
      const float4 wa = *(const float4*)&ws[(k + kk) * 16 + 0];   // broadcast b128
      const float4 wb = *(const float4*)&ws[(k + kk) * 16 + 4];
      const float4 wc = *(const float4*)&ws[(k + kk) * 16 + 8];
      const float4 wd = *(const float4*)&ws[(k + kk) * 16 + 12];
      accA[0]  = fmaf(pA, wa.x, accA[0]);   accB[0]  = fmaf(pB, wa.x, accB[0]);
      accA[1]  = fmaf(pA, wa.y, accA[1]);   accB[1]  = fmaf(pB, wa.y, accB[1]);
      accA[2]  = fmaf(pA, wa.z, accA[2]);   accB[2]  = fmaf(pB, wa.z, accB[2]);
      accA[3]  = fmaf(pA, wa.w, accA[3]);   accB[3]  = fmaf(pB, wa.w, accB[3]);
      accA[4]  = fmaf(pA, wb.x, accA[4]);   accB[4]  = fmaf(pB, wb.x, accB[4]);
      accA[5]  = fmaf(pA, wb.y, accA[5]);   accB[5]  = fmaf(pB, wb.y, accB[5]);
      accA[6]  = fmaf(pA, wb.z, accA[6]);   accB[6]  = fmaf(pB, wb.z, accB[6]);
      accA[7]  = fmaf(pA, wb.w, accA[7]);   accB[7]  = fmaf(pB, wb.w, accB[7]);
      accA[8]  = fmaf(pA, wc.x, accA[8]);   accB[8]  = fmaf(pB, wc.x, accB[8]);
      accA[9]  = fmaf(pA, wc.y, accA[9]);   accB[9]  = fmaf(pB, wc.y, accB[9]);
      accA[10] = fmaf(pA, wc.z, accA[10]);  accB[10] = fmaf(pB, wc.z, accB[10]);
      accA[11] = fmaf(pA, wc.w, accA[11]);  accB[11] = fmaf(pB, wc.w, accB[11]);
      accA[12] = fmaf(pA, wd.x, accA[12]);  accB[12] = fmaf(pB, wd.x, accB[12]);
      accA[13] = fmaf(pA, wd.y, accA[13]);  accB[13] = fmaf(pB, wd.y, accB[13]);
      accA[14] = fmaf(pA, wd.z, accA[14]);  accB[14] = fmaf(pB, wd.z, accB[14]);
      accA[15] = fmaf(pA, wd.w, accA[15]);  accB[15] = fmaf(pB, wd.w, accB[15]);
    }
  }
#pragma unroll
  for (int u = 0; u < 16; u++) {
    y2T[(size_t)(j0 + u) * NG + gA] = fmaxf(accA[u], 0.f);
    y2T[(size_t)(j0 + u) * NG + gB] = fmaxf(accB[u], 0.f);
  }
}

// out[g] = y2T[:,g] . out_W + out_b  -- lane = graph, coalesced, no shuffle
__global__ void k_out(const float* __restrict__ y2T, const float* __restrict__ ow,
                      const float* __restrict__ ob, float* __restrict__ out) {
  int g = blockIdx.x * 256 + threadIdx.x;
  float s0 = 0.f, s1 = 0.f, s2 = 0.f, s3 = 0.f;
#pragma unroll 4
  for (int j = 0; j < 512; j += 4) {
    s0 = fmaf(y2T[(size_t)(j + 0) * NG + g], ow[j + 0], s0);
    s1 = fmaf(y2T[(size_t)(j + 1) * NG + g], ow[j + 1], s1);
    s2 = fmaf(y2T[(size_t)(j + 2) * NG + g], ow[j + 2], s2);
    s3 = fmaf(y2T[(size_t)(j + 3) * NG + g], ow[j + 3], s3);
  }
  out[g] = (s0 + s1) + (s2 + s3) + ob[0];
}

extern "C" void kernel_launch(void* const* d_in, const int* in_sizes, int n_in,
                              void* d_out, int out_size, void* d_ws, size_t ws_size,
                              hipStream_t stream) {
  const float* x_mol    = (const float*)d_in[0];
  const float* x_adduct = (const float*)d_in[1];
  const int*   edge_src = (const int*)d_in[2];
  const int*   edge_dst = (const int*)d_in[3];
  const int*   graph_ids= (const int*)d_in[4];
  const float* gcn_W    = (const float*)d_in[5];
  const float* gcn_b    = (const float*)d_in[6];
  const float* d1W      = (const float*)d_in[7];
  const float* d1b      = (const float*)d_in[8];
  const float* d2W      = (const float*)d_in[9];
  const float* d2b      = (const float*)d_in[10];
  const float* oW       = (const float*)d_in[11];
  const float* obias    = (const float*)d_in[12];
  float* out = (float*)d_out;

  char* p = (char*)d_ws;
  auto alloc = [&](size_t bytes) {
    char* q = p;
    p += (bytes + 255) & ~(size_t)255;
    return q;
  };
  int*   counts   = (int*)alloc((size_t)NN * 4);
  int*   rp       = (int*)alloc((size_t)(NN + 1) * 4);
  int*   cursor   = (int*)alloc((size_t)NN * 4);
  int*   bsum     = (int*)alloc(1024 * 4);
  float* inv_deg  = (float*)alloc((size_t)NN * 4);
  int*   csr_src  = (int*)alloc((size_t)NE * 4);
  float* csr_norm = (float*)alloc((size_t)NE * 4);
  float* t        = (float*)alloc((size_t)NN * 64 * 4);
  float* h        = (float*)alloc((size_t)NN * 64 * 4);
  float* r        = (float*)alloc((size_t)NG * 64 * 4);
  float* y1T      = (float*)alloc((size_t)NG * 512 * 4);
  float* y2T      = (float*)alloc((size_t)NG * 512 * 4);

  hipMemsetAsync(counts, 0, (size_t)NN * 4, stream);
  k_count<<<NE / 256, 256, 0, stream>>>(edge_dst, counts);
  k_scan1<<<NN / 256, 256, 0, stream>>>(counts, rp, bsum);
  k_scan2<<<1, 1024, 0, stream>>>(bsum);
  k_scan3<<<NN / 256, 256, 0, stream>>>(counts, rp, bsum, cursor, inv_deg);
  k_fill<<<NE / 256, 256, 0, stream>>>(edge_src, edge_dst, counts, cursor, csr_src, csr_norm);

  const float* hin = x_mol;
  for (int L = 0; L < 3; L++) {
    k_transform<<<NN / 64, 256, 0, stream>>>(hin, gcn_W + (size_t)L * 64 * 64,
                                             gcn_b + (size_t)L * 64, t);
    k_aggregate<<<NN / 4, 256, 0, stream>>>(t, rp, csr_src, csr_norm, inv_deg, h);
    hin = h;
  }
  k_readout<<<NG / 4, 256, 0, stream>>>(h, graph_ids, r);
  k_dense1<<<NG / 8, 256, 0, stream>>>(r, x_adduct, d1W, d1b, y1T);
  k_dense2<<<512, 256, 0, stream>>>(y1T, d2W, d2b, y2T);
  k_out<<<NG / 256, 256, 0, stream>>>(y2T, oW, obias, out);
}

// Round 9
// 622.630 us; speedup vs baseline: 1.2311x; 1.1488x over previous
//
#include <hip/hip_runtime.h>

#define NN 262144   // nodes
#define NE 1048576  // edges
#define NG 8192     // graphs
#define FD 64       // feature dim
#define AD 8        // adduct dim
#define DN 512      // dense dim

__device__ __forceinline__ int lowerBound(const int* __restrict__ a, int n, int v) {
  int lo = 0, hi = n;
  while (lo < hi) { int mid = (lo + hi) >> 1; if (a[mid] < v) lo = mid + 1; else hi = mid; }
  return lo;
}

// ---------------- CSR build ----------------
__global__ void k_count(const int* __restrict__ dst, int* __restrict__ counts) {
  int e = blockIdx.x * 256 + threadIdx.x;
  if (e < NE) atomicAdd(&counts[dst[e]], 1);
}

__global__ void k_scan1(const int* __restrict__ counts, int* __restrict__ rp,
                        int* __restrict__ bsum) {
  __shared__ int s[256];
  int tid = threadIdx.x;
  int i = blockIdx.x * 256 + tid;
  int orig = counts[i];
  s[tid] = orig;
  __syncthreads();
  for (int off = 1; off < 256; off <<= 1) {
    int v = (tid >= off) ? s[tid - off] : 0;
    __syncthreads();
    s[tid] += v;
    __syncthreads();
  }
  rp[i] = s[tid] - orig;  // block-local exclusive scan
  if (tid == 255) bsum[blockIdx.x] = s[tid];
}

__global__ void k_scan2(int* __restrict__ bsum) {
  __shared__ int s[1024];
  int tid = threadIdx.x;
  int orig = bsum[tid];
  s[tid] = orig;
  __syncthreads();
  for (int off = 1; off < 1024; off <<= 1) {
    int v = (tid >= off) ? s[tid - off] : 0;
    __syncthreads();
    s[tid] += v;
    __syncthreads();
  }
  bsum[tid] = s[tid] - orig;  // exclusive
}

__global__ void k_scan3(const int* __restrict__ counts, int* __restrict__ rp,
                        const int* __restrict__ bsum, int* __restrict__ cursor,
                        float* __restrict__ inv_deg) {
  int i = blockIdx.x * 256 + threadIdx.x;
  int v = rp[i] + bsum[blockIdx.x];
  rp[i] = v;
  cursor[i] = v;
  inv_deg[i] = 1.0f / (float)(counts[i] + 1);
  if (i == 0) rp[NN] = NE;
}

__global__ void k_fill(const int* __restrict__ src, const int* __restrict__ dst,
                       const int* __restrict__ counts, int* __restrict__ cursor,
                       int* __restrict__ csr_src, float* __restrict__ csr_norm) {
  int e = blockIdx.x * 256 + threadIdx.x;
  if (e >= NE) return;
  int s = src[e], d = dst[e];
  float ds = (float)(counts[s] + 1);
  float dd = (float)(counts[d] + 1);
  int pos = atomicAdd(&cursor[d], 1);
  csr_src[pos] = s;
  csr_norm[pos] = rsqrtf(ds * dd);
}

// ---------------- GCN: t = h @ W + b ----------------
// Classic LDS-tiled GEMM (validated R4: ~28 us/layer, no scratch traffic).
#define HS 68  // hsT row stride (floats): 68*4=272 B, 16B-aligned, breaks pow2 banks
__global__ void __launch_bounds__(256) k_transform(const float* __restrict__ hin,
                                                   const float* __restrict__ W,
                                                   const float* __restrict__ b,
                                                   float* __restrict__ tout) {
  __shared__ float hsT[64 * HS];  // [k][n]  17.4 KB
  __shared__ float Ws[64 * 64];   // [k][c]  16 KB
  int tid = threadIdx.x;
  size_t base = (size_t)blockIdx.x * 64 * 64;

  const float4* h4 = (const float4*)(hin + base);
#pragma unroll
  for (int j = 0; j < 4; j++) {
    int f = tid + 256 * j;        // float4 index within 64x64 tile
    int n = f >> 4, kq = f & 15;  // node row, k-quad
    float4 v = h4[f];
    hsT[(4 * kq + 0) * HS + n] = v.x;
    hsT[(4 * kq + 1) * HS + n] = v.y;
    hsT[(4 * kq + 2) * HS + n] = v.z;
    hsT[(4 * kq + 3) * HS + n] = v.w;
  }
  const float4* w4 = (const float4*)W;
  float4* ws4 = (float4*)Ws;
#pragma unroll
  for (int j = 0; j < 4; j++) ws4[tid + 256 * j] = w4[tid + 256 * j];
  __syncthreads();

  int n0 = (tid >> 4) * 4;  // node quad (16-lane broadcast, free)
  int c0 = (tid & 15) * 4;  // col quad (contiguous 256B, free)
  float acc[4][4];
#pragma unroll
  for (int i = 0; i < 4; i++)
#pragma unroll
    for (int j = 0; j < 4; j++) acc[i][j] = b[c0 + j];

#pragma unroll 4
  for (int k = 0; k < 64; k++) {
    float4 av = *(const float4*)&hsT[k * HS + n0];  // ds_read_b128
    float4 bv = *(const float4*)&Ws[k * 64 + c0];   // ds_read_b128
    acc[0][0] = fmaf(av.x, bv.x, acc[0][0]);
    acc[0][1] = fmaf(av.x, bv.y, acc[0][1]);
    acc[0][2] = fmaf(av.x, bv.z, acc[0][2]);
    acc[0][3] = fmaf(av.x, bv.w, acc[0][3]);
    acc[1][0] = fmaf(av.y, bv.x, acc[1][0]);
    acc[1][1] = fmaf(av.y, bv.y, acc[1][1]);
    acc[1][2] = fmaf(av.y, bv.z, acc[1][2]);
    acc[1][3] = fmaf(av.y, bv.w, acc[1][3]);
    acc[2][0] = fmaf(av.z, bv.x, acc[2][0]);
    acc[2][1] = fmaf(av.z, bv.y, acc[2][1]);
    acc[2][2] = fmaf(av.z, bv.z, acc[2][2]);
    acc[2][3] = fmaf(av.z, bv.w, acc[2][3]);
    acc[3][0] = fmaf(av.w, bv.x, acc[3][0]);
    acc[3][1] = fmaf(av.w, bv.y, acc[3][1]);
    acc[3][2] = fmaf(av.w, bv.z, acc[3][2]);
    acc[3][3] = fmaf(av.w, bv.w, acc[3][3]);
  }

  float4* o4 = (float4*)(tout + base);
#pragma unroll
  for (int i = 0; i < 4; i++) {
    o4[((n0 + i) * 64 + c0) >> 2] =
        make_float4(acc[i][0], acc[i][1], acc[i][2], acc[i][3]);
  }
}

// ---------------- Aggregate: h = relu(sum_{e->n} norm*t[src] + t[n]/deg) ----------------
// R8 was VMEM-issue/latency bound: lane=feature meant 1 full-wave gather instr
// per row, 4 rows in flight. Now 16 lanes per row (float4/lane): one wave
// processes 4 nodes; each gather instr serves 4 distinct rows (1 KB/instr),
// and unroll-2 per node stream keeps 8 rows in flight per wave.
__global__ void k_aggregate(const float* __restrict__ t, const int* __restrict__ rp,
                            const int* __restrict__ csr_src, const float* __restrict__ csr_norm,
                            const float* __restrict__ inv_deg, float* __restrict__ hout) {
  int tid = threadIdx.x;
  int grp = tid >> 4;   // 16 node-groups per 256-thread block
  int ln  = tid & 15;   // feature quad within row
  int n = blockIdx.x * 16 + grp;
  int beg = rp[n], end = rp[n + 1];
  const float4* t4 = (const float4*)t;

  float4 v = t4[(size_t)n * 16 + ln];
  float sdeg = inv_deg[n];
  float4 a0 = make_float4(v.x * sdeg, v.y * sdeg, v.z * sdeg, v.w * sdeg);
  float4 a1 = make_float4(0.f, 0.f, 0.f, 0.f);

  int idx = beg;
  for (; idx + 2 <= end; idx += 2) {
    int s0 = csr_src[idx + 0];
    int s1 = csr_src[idx + 1];
    float w0 = csr_norm[idx + 0];
    float w1 = csr_norm[idx + 1];
    float4 v0 = t4[(size_t)s0 * 16 + ln];
    float4 v1 = t4[(size_t)s1 * 16 + ln];
    a0.x = fmaf(w0, v0.x, a0.x);
    a0.y = fmaf(w0, v0.y, a0.y);
    a0.z = fmaf(w0, v0.z, a0.z);
    a0.w = fmaf(w0, v0.w, a0.w);
    a1.x = fmaf(w1, v1.x, a1.x);
    a1.y = fmaf(w1, v1.y, a1.y);
    a1.z = fmaf(w1, v1.z, a1.z);
    a1.w = fmaf(w1, v1.w, a1.w);
  }
  if (idx < end) {
    int s = csr_src[idx];
    float w = csr_norm[idx];
    float4 v0 = t4[(size_t)s * 16 + ln];
    a0.x = fmaf(w, v0.x, a0.x);
    a0.y = fmaf(w, v0.y, a0.y);
    a0.z = fmaf(w, v0.z, a0.z);
    a0.w = fmaf(w, v0.w, a0.w);
  }
  float4 r;
  r.x = fmaxf(a0.x + a1.x, 0.f);
  r.y = fmaxf(a0.y + a1.y, 0.f);
  r.z = fmaxf(a0.z + a1.z, 0.f);
  r.w = fmaxf(a0.w + a1.w, 0.f);
  ((float4*)hout)[(size_t)n * 16 + ln] = r;
}

// ---------------- Readout: graph_ids sorted -> binary-search ranges ----------------
// Same 16-lane/float4 repack: 4 graphs per wave, unroll-2 row streams.
__global__ void k_readout(const float* __restrict__ h, const int* __restrict__ gids,
                          float* __restrict__ r) {
  int tid = threadIdx.x;
  int grp = tid >> 4, ln = tid & 15;
  int g = blockIdx.x * 16 + grp;
  int lo = lowerBound(gids, NN, g);
  int hi = lowerBound(gids, NN, g + 1);
  const float4* h4 = (const float4*)h;
  float4 a0 = make_float4(0.f, 0.f, 0.f, 0.f);
  float4 a1 = make_float4(0.f, 0.f, 0.f, 0.f);
  int n = lo;
  for (; n + 2 <= hi; n += 2) {
    float4 v0 = h4[(size_t)n * 16 + ln];
    float4 v1 = h4[(size_t)(n + 1) * 16 + ln];
    a0.x += v0.x; a0.y += v0.y; a0.z += v0.z; a0.w += v0.w;
    a1.x += v1.x; a1.y += v1.y; a1.z += v1.z; a1.w += v1.w;
  }
  if (n < hi) {
    float4 v0 = h4[(size_t)n * 16 + ln];
    a0.x += v0.x; a0.y += v0.y; a0.z += v0.z; a0.w += v0.w;
  }
  ((float4*)r)[(size_t)g * 16 + ln] =
      make_float4(a0.x + a1.x, a0.y + a1.y, a0.z + a1.z, a0.w + a1.w);
}

// ---------------- Dense head ----------------
// y1T[j][g] = relu(b1[j] + sum_k concat(r,xa)[g][k] * W1[k][j])
// TRANSPOSED output (g-contiguous rows) so dense2/out use lane=graph coalesced.
__global__ void __launch_bounds__(256) k_dense1(const float* __restrict__ r,
                                                const float* __restrict__ xa,
                                                const float* __restrict__ W1,
                                                const float* __restrict__ b1,
                                                float* __restrict__ y1T) {
  __shared__ float xs[8 * 72];
  int tid = threadIdx.x;
  int g0 = blockIdx.x * 8;
  for (int i = tid; i < 8 * 72; i += 256) {
    int g = i / 72, k = i % 72;
    xs[i] = (k < 64) ? r[(size_t)(g0 + g) * 64 + k] : xa[(size_t)(g0 + g) * 8 + (k - 64)];
  }
  __syncthreads();
  float acc[8][2];
#pragma unroll
  for (int g = 0; g < 8; g++) { acc[g][0] = 0.f; acc[g][1] = 0.f; }
  for (int k = 0; k < 72; k++) {
    float w0 = W1[k * 512 + tid];
    float w1 = W1[k * 512 + 256 + tid];
#pragma unroll
    for (int g = 0; g < 8; g++) {
      float xv = xs[g * 72 + k];  // wave-uniform broadcast
      acc[g][0] = fmaf(xv, w0, acc[g][0]);
      acc[g][1] = fmaf(xv, w1, acc[g][1]);
    }
  }
  float bb0 = b1[tid], bb1 = b1[256 + tid];
  float4 v;
  v = make_float4(fmaxf(acc[0][0] + bb0, 0.f), fmaxf(acc[1][0] + bb0, 0.f),
                  fmaxf(acc[2][0] + bb0, 0.f), fmaxf(acc[3][0] + bb0, 0.f));
  *(float4*)&y1T[(size_t)tid * NG + g0] = v;
  v = make_float4(fmaxf(acc[4][0] + bb0, 0.f), fmaxf(acc[5][0] + bb0, 0.f),
                  fmaxf(acc[6][0] + bb0, 0.f), fmaxf(acc[7][0] + bb0, 0.f));
  *(float4*)&y1T[(size_t)tid * NG + g0 + 4] = v;
  v = make_float4(fmaxf(acc[0][1] + bb1, 0.f), fmaxf(acc[1][1] + bb1, 0.f),
                  fmaxf(acc[2][1] + bb1, 0.f), fmaxf(acc[3][1] + bb1, 0.f));
  *(float4*)&y1T[(size_t)(256 + tid) * NG + g0] = v;
  v = make_float4(fmaxf(acc[4][1] + bb1, 0.f), fmaxf(acc[5][1] + bb1, 0.f),
                  fmaxf(acc[6][1] + bb1, 0.f), fmaxf(acc[7][1] + bb1, 0.f));
  *(float4*)&y1T[(size_t)(256 + tid) * NG + g0 + 4] = v;
}

// y2T = relu(W2^T @ y1T + b2), lane = graph, W2 slice in LDS, 2 graphs/thread
// (validated R8: fma:ds_read 8:1).
__global__ void __launch_bounds__(256) k_dense2(const float* __restrict__ xT,
                                                const float* __restrict__ W2,
                                                const float* __restrict__ b2,
                                                float* __restrict__ y2T) {
  __shared__ float ws[512 * 16];  // [k][j-slice] 32 KB
  int tid = threadIdx.x;
  int gA = (blockIdx.x & 15) * 512 + tid;  // graphs [gb*512 .. gb*512+512)
  int gB = gA + 256;
  int j0 = (blockIdx.x >> 4) * 16;
  {
    int u = tid & 15, kb = tid >> 4;  // 16 k-rows per sweep
#pragma unroll
    for (int i = 0; i < 32; i++) {
      int k = kb + 16 * i;
      ws[k * 16 + u] = W2[(size_t)k * 512 + j0 + u];  // 64B segs, coalesced per 16 lanes
    }
  }
  float accA[16], accB[16];
#pragma unroll
  for (int u = 0; u < 16; u++) { float bb = b2[j0 + u]; accA[u] = bb; accB[u] = bb; }
  __syncthreads();

  float pa0 = xT[gA];
  float pa1 = xT[(size_t)1 * NG + gA];
  float pa2 = xT[(size_t)2 * NG + gA];
  float pa3 = xT[(size_t)3 * NG + gA];
  float pb0 = xT[gB];
  float pb1 = xT[(size_t)1 * NG + gB];
  float pb2 = xT[(size_t)2 * NG + gB];
  float pb3 = xT[(size_t)3 * NG + gB];
#pragma unroll 1
  for (int k = 0; k < 512; k += 4) {
    float a0 = pa0, a1 = pa1, a2 = pa2, a3 = pa3;
    float b0 = pb0, b1 = pb1, b2v = pb2, b3 = pb3;
    if (k + 4 < 512) {
      pa0 = xT[(size_t)(k + 4) * NG + gA];
      pa1 = xT[(size_t)(k + 5) * NG + gA];
      pa2 = xT[(size_t)(k + 6) * NG + gA];
      pa3 = xT[(size_t)(k + 7) * NG + gA];
      pb0 = xT[(size_t)(k + 4) * NG + gB];
      pb1 = xT[(size_t)(k + 5) * NG + gB];
      pb2 = xT[(size_t)(k + 6) * NG + gB];
      pb3 = xT[(size_t)(k + 7) * NG + gB];
    }
#pragma unroll
    for (int kk = 0; kk < 4; kk++) {
      float pA = (kk == 0) ? a0 : (kk == 1) ? a1 : (kk == 2) ? a2 : a3;
      float pB = (kk == 0) ? b0 : (kk == 1) ? b1 : (kk == 2) ? b2v : b3;
      const float4 wa = *(const float4*)&ws[(k + kk) * 16 + 0];   // broadcast b128
      const float4 wb = *(const float4*)&ws[(k + kk) * 16 + 4];
      const float4 wc = *(const float4*)&ws[(k + kk) * 16 + 8];
      const float4 wd = *(const float4*)&ws[(k + kk) * 16 + 12];
      accA[0]  = fmaf(pA, wa.x, accA[0]);   accB[0]  = fmaf(pB, wa.x, accB[0]);
      accA[1]  = fmaf(pA, wa.y, accA[1]);   accB[1]  = fmaf(pB, wa.y, accB[1]);
      accA[2]  = fmaf(pA, wa.z, accA[2]);   accB[2]  = fmaf(pB, wa.z, accB[2]);
      accA[3]  = fmaf(pA, wa.w, accA[3]);   accB[3]  = fmaf(pB, wa.w, accB[3]);
      accA[4]  = fmaf(pA, wb.x, accA[4]);   accB[4]  = fmaf(pB, wb.x, accB[4]);
      accA[5]  = fmaf(pA, wb.y, accA[5]);   accB[5]  = fmaf(pB, wb.y, accB[5]);
      accA[6]  = fmaf(pA, wb.z, accA[6]);   accB[6]  = fmaf(pB, wb.z, accB[6]);
      accA[7]  = fmaf(pA, wb.w, accA[7]);   accB[7]  = fmaf(pB, wb.w, accB[7]);
      accA[8]  = fmaf(pA, wc.x, accA[8]);   accB[8]  = fmaf(pB, wc.x, accB[8]);
      accA[9]  = fmaf(pA, wc.y, accA[9]);   accB[9]  = fmaf(pB, wc.y, accB[9]);
      accA[10] = fmaf(pA, wc.z, accA[10]);  accB[10] = fmaf(pB, wc.z, accB[10]);
      accA[11] = fmaf(pA, wc.w, accA[11]);  accB[11] = fmaf(pB, wc.w, accB[11]);
      accA[12] = fmaf(pA, wd.x, accA[12]);  accB[12] = fmaf(pB, wd.x, accB[12]);
      accA[13] = fmaf(pA, wd.y, accA[13]);  accB[13] = fmaf(pB, wd.y, accB[13]);
      accA[14] = fmaf(pA, wd.z, accA[14]);  accB[14] = fmaf(pB, wd.z, accB[14]);
      accA[15] = fmaf(pA, wd.w, accA[15]);  accB[15] = fmaf(pB, wd.w, accB[15]);
    }
  }
#pragma unroll
  for (int u = 0; u < 16; u++) {
    y2T[(size_t)(j0 + u) * NG + gA] = fmaxf(accA[u], 0.f);
    y2T[(size_t)(j0 + u) * NG + gB] = fmaxf(accB[u], 0.f);
  }
}

// out[g] = y2T[:,g] . out_W + out_b  -- lane = graph, coalesced, no shuffle
__global__ void k_out(const float* __restrict__ y2T, const float* __restrict__ ow,
                      const float* __restrict__ ob, float* __restrict__ out) {
  int g = blockIdx.x * 256 + threadIdx.x;
  float s0 = 0.f, s1 = 0.f, s2 = 0.f, s3 = 0.f;
#pragma unroll 4
  for (int j = 0; j < 512; j += 4) {
    s0 = fmaf(y2T[(size_t)(j + 0) * NG + g], ow[j + 0], s0);
    s1 = fmaf(y2T[(size_t)(j + 1) * NG + g], ow[j + 1], s1);
    s2 = fmaf(y2T[(size_t)(j + 2) * NG + g], ow[j + 2], s2);
    s3 = fmaf(y2T[(size_t)(j + 3) * NG + g], ow[j + 3], s3);
  }
  out[g] = (s0 + s1) + (s2 + s3) + ob[0];
}

extern "C" void kernel_launch(void* const* d_in, const int* in_sizes, int n_in,
                              void* d_out, int out_size, void* d_ws, size_t ws_size,
                              hipStream_t stream) {
  const float* x_mol    = (const float*)d_in[0];
  const float* x_adduct = (const float*)d_in[1];
  const int*   edge_src = (const int*)d_in[2];
  const int*   edge_dst = (const int*)d_in[3];
  const int*   graph_ids= (const int*)d_in[4];
  const float* gcn_W    = (const float*)d_in[5];
  const float* gcn_b    = (const float*)d_in[6];
  const float* d1W      = (const float*)d_in[7];
  const float* d1b      = (const float*)d_in[8];
  const float* d2W      = (const float*)d_in[9];
  const float* d2b      = (const float*)d_in[10];
  const float* oW       = (const float*)d_in[11];
  const float* obias    = (const float*)d_in[12];
  float* out = (float*)d_out;

  char* p = (char*)d_ws;
  auto alloc = [&](size_t bytes) {
    char* q = p;
    p += (bytes + 255) & ~(size_t)255;
    return q;
  };
  int*   counts   = (int*)alloc((size_t)NN * 4);
  int*   rp       = (int*)alloc((size_t)(NN + 1) * 4);
  int*   cursor   = (int*)alloc((size_t)NN * 4);
  int*   bsum     = (int*)alloc(1024 * 4);
  float* inv_deg  = (float*)alloc((size_t)NN * 4);
  int*   csr_src  = (int*)alloc((size_t)NE * 4);
  float* csr_norm = (float*)alloc((size_t)NE * 4);
  float* t        = (float*)alloc((size_t)NN * 64 * 4);
  float* h        = (float*)alloc((size_t)NN * 64 * 4);
  float* r        = (float*)alloc((size_t)NG * 64 * 4);
  float* y1T      = (float*)alloc((size_t)NG * 512 * 4);
  float* y2T      = (float*)alloc((size_t)NG * 512 * 4);

  hipMemsetAsync(counts, 0, (size_t)NN * 4, stream);
  k_count<<<NE / 256, 256, 0, stream>>>(edge_dst, counts);
  k_scan1<<<NN / 256, 256, 0, stream>>>(counts, rp, bsum);
  k_scan2<<<1, 1024, 0, stream>>>(bsum);
  k_scan3<<<NN / 256, 256, 0, stream>>>(counts, rp, bsum, cursor, inv_deg);
  k_fill<<<NE / 256, 256, 0, stream>>>(edge_src, edge_dst, counts, cursor, csr_src, csr_norm);

  const float* hin = x_mol;
  for (int L = 0; L < 3; L++) {
    k_transform<<<NN / 64, 256, 0, stream>>>(hin, gcn_W + (size_t)L * 64 * 64,
                                             gcn_b + (size_t)L * 64, t);
    k_aggregate<<<NN / 16, 256, 0, stream>>>(t, rp, csr_src, csr_norm, inv_deg, h);
    hin = h;
  }
  k_readout<<<NG / 16, 256, 0, stream>>>(h, graph_ids, r);
  k_dense1<<<NG / 8, 256, 0, stream>>>(r, x_adduct, d1W, d1b, y1T);
  k_dense2<<<512, 256, 0, stream>>>(y1T, d2W, d2b, y2T);
  k_out<<<NG / 256, 256, 0, stream>>>(y2T, oW, obias, out);
}